// Round 3
// baseline (221.509 us; speedup 1.0000x reference)
//
#include <hip/hip_runtime.h>

#define N_NODES 50000
#define N_EDGES 800000
#define D 64
#define NSLICE 8
#define SLICE_N ((N_NODES + NSLICE - 1) / NSLICE)   // 6250
#define BCAP 64        // bucket capacity; deg ~ Poisson(16), P(deg>=64) ~ 1e-19

// persistent fused-kernel geometry: 768 blocks * 4 waves = 3072 waves
// (~3 waves/SIMD at ~170 VGPR), 17 nodes/wave covers 50000.
#define FAGG_BLOCKS 768
#define NPW 17

// float -> bf16 (round-to-nearest-even), as raw ushort
__device__ __forceinline__ unsigned short f2bf(float f) {
    unsigned int u = __builtin_bit_cast(unsigned int, f);
    u += 0x7fffu + ((u >> 16) & 1u);
    return (unsigned short)(u >> 16);
}
__device__ __forceinline__ float bflo(unsigned int u) {
    return __builtin_bit_cast(float, u << 16);
}
__device__ __forceinline__ float bfhi(unsigned int u) {
    return __builtin_bit_cast(float, u & 0xffff0000u);
}

// ---------------- transform body (k_pre's fused layer-0 role only) ----------
// lane = output column, W column in 64 VGPRs, h rows as wave-uniform float4.
// Known latency-bound but k_pre is frozen this round (46.8 us, stable counters).
__device__ __forceinline__ void xform_body(const float* __restrict__ h,
        const float* __restrict__ Ws, const float* __restrict__ Wn,
        const float* __restrict__ b,
        float* __restrict__ yS, unsigned short* __restrict__ yN,
        int gwave, int nwaves, int lane) {
    int mat = gwave & 1;
    const float* W = mat ? Wn : Ws;

    float w[D];
#pragma unroll
    for (int k = 0; k < D; ++k) w[k] = W[k * D + lane];
    float bj = mat ? 0.f : b[lane];

    const int ngroups = (N_NODES + 3) / 4;   // 12500, exact
    for (int g = gwave >> 1; g < ngroups; g += (nwaves >> 1)) {
        const float* x0 = h + (size_t)(g * 4) * D;
        float a0 = bj, a1 = bj, a2 = bj, a3 = bj;
#pragma unroll
        for (int kq = 0; kq < 16; ++kq) {
            float4 v0 = *(const float4*)(x0 + 0 * D + kq * 4);
            float4 v1 = *(const float4*)(x0 + 1 * D + kq * 4);
            float4 v2 = *(const float4*)(x0 + 2 * D + kq * 4);
            float4 v3 = *(const float4*)(x0 + 3 * D + kq * 4);
            a0 = fmaf(v0.x, w[kq * 4 + 0], a0);
            a1 = fmaf(v1.x, w[kq * 4 + 0], a1);
            a2 = fmaf(v2.x, w[kq * 4 + 0], a2);
            a3 = fmaf(v3.x, w[kq * 4 + 0], a3);
            a0 = fmaf(v0.y, w[kq * 4 + 1], a0);
            a1 = fmaf(v1.y, w[kq * 4 + 1], a1);
            a2 = fmaf(v2.y, w[kq * 4 + 1], a2);
            a3 = fmaf(v3.y, w[kq * 4 + 1], a3);
            a0 = fmaf(v0.z, w[kq * 4 + 2], a0);
            a1 = fmaf(v1.z, w[kq * 4 + 2], a1);
            a2 = fmaf(v2.z, w[kq * 4 + 2], a2);
            a3 = fmaf(v3.z, w[kq * 4 + 2], a3);
            a0 = fmaf(v0.w, w[kq * 4 + 3], a0);
            a1 = fmaf(v1.w, w[kq * 4 + 3], a1);
            a2 = fmaf(v2.w, w[kq * 4 + 3], a2);
            a3 = fmaf(v3.w, w[kq * 4 + 3], a3);
        }
        size_t base = (size_t)(g * 4) * D + lane;
        if (mat) {
            yN[base + 0 * D] = f2bf(a0);
            yN[base + 1 * D] = f2bf(a1);
            yN[base + 2 * D] = f2bf(a2);
            yN[base + 3 * D] = f2bf(a3);
        } else {
            yS[base + 0 * D] = a0;
            yS[base + 1 * D] = a1;
            yS[base + 2 * D] = a2;
            yS[base + 3 * D] = a3;
        }
    }
}

// ---------------- FUSED stage 1: layer-0 transform (blocks 0..1023) ∥ CSR fill ----
// Unchanged from R11 (slice s pinned to XCD s via bid&7; int4 edge loads).
__global__ __launch_bounds__(256) void k_pre(const float* __restrict__ x,
        const float* __restrict__ Ws0, const float* __restrict__ Wn0,
        const float* __restrict__ b0,
        float* __restrict__ yS, unsigned short* __restrict__ yN,
        const int* __restrict__ src, const int* __restrict__ dst,
        int* __restrict__ cnt, int* __restrict__ csr) {
    int bid = (int)blockIdx.x;
    if (bid < 1024) {
        int lane = threadIdx.x & 63;
        int gwave = __builtin_amdgcn_readfirstlane(bid * 4 + (int)(threadIdx.x >> 6));
        xform_body(x, Ws0, Wn0, b0, yS, yN, gwave, 4096, lane);
    } else {
        int slice = bid & 7;                 // 1024 % 8 == 0 -> slice == XCD id
        int lo = slice * SLICE_N, hi = lo + SLICE_N;
        int gblk = (bid - 1024) >> 3;        // 0..127 within the slice
        const int4* d4p = (const int4*)dst;
        const int4* s4p = (const int4*)src;
        const int NV = N_EDGES / 4;          // 200000, exact
        for (int v = gblk * 256 + (int)threadIdx.x; v < NV; v += 128 * 256) {
            int4 d4 = d4p[v];
            int4 s4 = s4p[v];
            if (d4.x >= lo && d4.x < hi) { int p = atomicAdd(&cnt[d4.x], 1); csr[(d4.x << 6) + p] = s4.x; }
            if (d4.y >= lo && d4.y < hi) { int p = atomicAdd(&cnt[d4.y], 1); csr[(d4.y << 6) + p] = s4.y; }
            if (d4.z >= lo && d4.z < hi) { int p = atomicAdd(&cnt[d4.z], 1); csr[(d4.z << 6) + p] = s4.z; }
            if (d4.w >= lo && d4.w < hi) { int p = atomicAdd(&cnt[d4.w], 1); csr[(d4.w << 6) + p] = s4.w; }
        }
    }
}

// shared phase-1 macro: deg-adaptive gather+masked-fma rounds on a bf16 table
#define ROUND16(E0)                                                         \
    {                                                                       \
        int i0 = (E0) + q, i1 = i0 + 8;                                     \
        int b0_ = bucket[i0], b1_ = bucket[i1];                             \
        unsigned a0 = (i0 < deg) ? ((unsigned)b0_ << 7) : 0u;               \
        unsigned a1 = (i1 < deg) ? ((unsigned)b1_ << 7) : 0u;               \
        float m0 = (i0 < deg) ? 1.f : 0.f;                                  \
        float m1 = (i1 < deg) ? 1.f : 0.f;                                  \
        uint4 u0 = *(const uint4*)(tb + a0 + foff);                         \
        uint4 u1 = *(const uint4*)(tb + a1 + foff);                         \
        s0 = fmaf(m0, bflo(u0.x), s0); s0 = fmaf(m1, bflo(u1.x), s0);       \
        s1 = fmaf(m0, bfhi(u0.x), s1); s1 = fmaf(m1, bfhi(u1.x), s1);       \
        s2 = fmaf(m0, bflo(u0.y), s2); s2 = fmaf(m1, bflo(u1.y), s2);       \
        s3 = fmaf(m0, bfhi(u0.y), s3); s3 = fmaf(m1, bfhi(u1.y), s3);       \
        s4 = fmaf(m0, bflo(u0.z), s4); s4 = fmaf(m1, bflo(u1.z), s4);       \
        s5 = fmaf(m0, bfhi(u0.z), s5); s5 = fmaf(m1, bfhi(u1.z), s5);       \
        s6 = fmaf(m0, bflo(u0.w), s6); s6 = fmaf(m1, bflo(u1.w), s6);       \
        s7 = fmaf(m0, bfhi(u0.w), s7); s7 = fmaf(m1, bfhi(u1.w), s7);       \
    }

// ---------------- R13: FUSED layer-0 aggregate + layer-1 transform ----------------
// Persistent waves (3072), one node at a time, 17 nodes/wave.
// Phase 1 = exact old k_aggf body -> h-row lives in registers (lane (q,fq)
// holds feature f=fq*8+q), relu'd.  NO h write to HBM.
// Phase 2 = per-wave 64x64 matvec: Ws1/Wn1 COLUMNS held per-lane (128 VGPRs,
// loaded once per wave, amortized over 17 nodes); h[k] broadcast via
// v_readlane from lane L(k)=((k&7)<<3)|(k>>3) into an SGPR, then 2 FMAs.
// Zero memory traffic in the inner loop; ascending-k accumulation ->
// bit-identical to the retired k_xform.
__global__ __launch_bounds__(256) void k_fagg0(const char* __restrict__ yN0,
        const float* __restrict__ yS0,
        const int* __restrict__ cnt, const int* __restrict__ csr,
        const float* __restrict__ Ws1, const float* __restrict__ Wn1,
        const float* __restrict__ b1,
        float* __restrict__ yS1, unsigned short* __restrict__ yN1) {
    int lane = threadIdx.x & 63;
    int wid = __builtin_amdgcn_readfirstlane((int)((blockIdx.x * blockDim.x + threadIdx.x) >> 6));
    int q = lane >> 3;
    int fq = lane & 7;
    unsigned foff = (unsigned)fq * 16u;
    int f = fq * 8 + q;                     // feature this lane owns after reduce

    // layer-1 weight columns for output col j = lane (amortized over NPW nodes)
    float ws[D], wn[D];
#pragma unroll
    for (int k = 0; k < D; ++k) ws[k] = Ws1[k * D + lane];
#pragma unroll
    for (int k = 0; k < D; ++k) wn[k] = Wn1[k * D + lane];
    float bj = b1[lane];

    int n0 = wid * NPW;
    int n1 = n0 + NPW; if (n1 > N_NODES) n1 = N_NODES;
    for (int node = n0; node < n1; ++node) {
        int deg = cnt[node];
        const int* bucket = csr + (node << 6);
        const char* tb = yN0;

        float s0 = 0.f, s1 = 0.f, s2 = 0.f, s3 = 0.f;
        float s4 = 0.f, s5 = 0.f, s6 = 0.f, s7 = 0.f;

        ROUND16(0)
        if (deg > 16) ROUND16(16)
        if (deg > 32) {
            ROUND16(32)
            if (deg > 48) ROUND16(48)
        }

        s0 += __shfl_xor(s0, 8, 64); s0 += __shfl_xor(s0, 16, 64); s0 += __shfl_xor(s0, 32, 64);
        s1 += __shfl_xor(s1, 8, 64); s1 += __shfl_xor(s1, 16, 64); s1 += __shfl_xor(s1, 32, 64);
        s2 += __shfl_xor(s2, 8, 64); s2 += __shfl_xor(s2, 16, 64); s2 += __shfl_xor(s2, 32, 64);
        s3 += __shfl_xor(s3, 8, 64); s3 += __shfl_xor(s3, 16, 64); s3 += __shfl_xor(s3, 32, 64);
        s4 += __shfl_xor(s4, 8, 64); s4 += __shfl_xor(s4, 16, 64); s4 += __shfl_xor(s4, 32, 64);
        s5 += __shfl_xor(s5, 8, 64); s5 += __shfl_xor(s5, 16, 64); s5 += __shfl_xor(s5, 32, 64);
        s6 += __shfl_xor(s6, 8, 64); s6 += __shfl_xor(s6, 16, 64); s6 += __shfl_xor(s6, 32, 64);
        s7 += __shfl_xor(s7, 8, 64); s7 += __shfl_xor(s7, 16, 64); s7 += __shfl_xor(s7, 32, 64);

        float sv = (q == 0) ? s0 : (q == 1) ? s1 : (q == 2) ? s2 : (q == 3) ? s3
                 : (q == 4) ? s4 : (q == 5) ? s5 : (q == 6) ? s6 : s7;
        float self = yS0[(size_t)node * D + f];
        float inv = 1.0f / fmaxf((float)deg, 1.0f);
        float hrow = fmaxf(self + sv * inv, 0.f);   // h[node][f], relu'd (2x relu idempotent)

        // phase 2: yS1[node][lane] = b1 + sum_k h[k]*Ws1[k][lane]; yN1 likewise (bf16)
        float acc_s = bj;
        float acc_n = 0.f;
        unsigned hbits = __builtin_bit_cast(unsigned, hrow);
#pragma unroll
        for (int k = 0; k < D; ++k) {
            // lane holding feature k: L(k) = ((k&7)<<3) | (k>>3)
            unsigned hb = __builtin_amdgcn_readlane(hbits, ((k & 7) << 3) | (k >> 3));
            float hk = __builtin_bit_cast(float, hb);
            acc_s = fmaf(hk, ws[k], acc_s);
            acc_n = fmaf(hk, wn[k], acc_n);
        }

        yS1[(size_t)node * D + lane] = acc_s;
        yN1[(size_t)node * D + lane] = f2bf(acc_n);
    }
}

// ---------------- fused mean-aggregate + self + epilogue (final layer, unchanged) ----
__global__ __launch_bounds__(256) void k_aggf(const char* __restrict__ yN,
        const float* __restrict__ yS,
        const int* __restrict__ cnt, const int* __restrict__ csr,
        float* __restrict__ out, int relu) {
    int node = __builtin_amdgcn_readfirstlane((blockIdx.x * blockDim.x + threadIdx.x) >> 6);
    int lane = threadIdx.x & 63;
    int q = lane >> 3;          // edge sub-slot 0..7
    int fq = lane & 7;          // uint4 slot within the 128 B row
    int deg = cnt[node];
    const int* bucket = csr + (node << 6);
    const char* tb = yN;
    unsigned foff = (unsigned)fq * 16u;

    float s0 = 0.f, s1 = 0.f, s2 = 0.f, s3 = 0.f;
    float s4 = 0.f, s5 = 0.f, s6 = 0.f, s7 = 0.f;

    ROUND16(0)                          // deg<=16: 53% of nodes stop here
    if (deg > 16) ROUND16(16)           // ~44%
    if (deg > 32) {                     // ~3%
        ROUND16(32)
        if (deg > 48) ROUND16(48)       // ~1e-4
    }

    s0 += __shfl_xor(s0, 8, 64); s0 += __shfl_xor(s0, 16, 64); s0 += __shfl_xor(s0, 32, 64);
    s1 += __shfl_xor(s1, 8, 64); s1 += __shfl_xor(s1, 16, 64); s1 += __shfl_xor(s1, 32, 64);
    s2 += __shfl_xor(s2, 8, 64); s2 += __shfl_xor(s2, 16, 64); s2 += __shfl_xor(s2, 32, 64);
    s3 += __shfl_xor(s3, 8, 64); s3 += __shfl_xor(s3, 16, 64); s3 += __shfl_xor(s3, 32, 64);
    s4 += __shfl_xor(s4, 8, 64); s4 += __shfl_xor(s4, 16, 64); s4 += __shfl_xor(s4, 32, 64);
    s5 += __shfl_xor(s5, 8, 64); s5 += __shfl_xor(s5, 16, 64); s5 += __shfl_xor(s5, 32, 64);
    s6 += __shfl_xor(s6, 8, 64); s6 += __shfl_xor(s6, 16, 64); s6 += __shfl_xor(s6, 32, 64);
    s7 += __shfl_xor(s7, 8, 64); s7 += __shfl_xor(s7, 16, 64); s7 += __shfl_xor(s7, 32, 64);

    float sv = (q == 0) ? s0 : (q == 1) ? s1 : (q == 2) ? s2 : (q == 3) ? s3
             : (q == 4) ? s4 : (q == 5) ? s5 : (q == 6) ? s6 : s7;
    int f = fq * 8 + q;                      // feature this lane writes
    float self = yS[(size_t)node * D + f];
    float inv = 1.0f / fmaxf((float)deg, 1.0f);
    float acc = self + sv * inv;
    if (relu) acc = fmaxf(acc, 0.f);
    out[(size_t)node * D + f] = acc;
}

extern "C" void kernel_launch(void* const* d_in, const int* in_sizes, int n_in,
                              void* d_out, int out_size, void* d_ws, size_t ws_size,
                              hipStream_t stream) {
    const float* x   = (const float*)d_in[0];
    const int*   src = (const int*)d_in[1];
    const int*   dst = (const int*)d_in[2];
    const float* Ws0 = (const float*)d_in[3];
    const float* Wn0 = (const float*)d_in[4];
    const float* b0  = (const float*)d_in[5];
    const float* Ws1 = (const float*)d_in[6];
    const float* Wn1 = (const float*)d_in[7];
    const float* b1  = (const float*)d_in[8];
    float* out = (float*)d_out;

    // workspace layout (layer-0 and layer-1 intermediates now separate:
    // k_fagg0 reads yS0/yN0 while writing yS1/yN1)
    char* p = (char*)d_ws;
    float*          yS0 = (float*)p;          p += (size_t)N_NODES * D * sizeof(float);
    unsigned short* yN0 = (unsigned short*)p; p += (size_t)N_NODES * D * sizeof(unsigned short);
    float*          yS1 = (float*)p;          p += (size_t)N_NODES * D * sizeof(float);
    unsigned short* yN1 = (unsigned short*)p; p += (size_t)N_NODES * D * sizeof(unsigned short);
    int* cnt = (int*)p;                       p += (size_t)N_NODES * sizeof(int);
    int* csr = (int*)p;                       p += (size_t)N_NODES * BCAP * sizeof(int);

    const int aggBlocks = (N_NODES + 3) / 4;     // 12500: wave per node, exact

    // tiny cnt zero (200 KB), stream-ordered before the fused stage
    hipMemsetAsync(cnt, 0, (size_t)N_NODES * sizeof(int), stream);

    // stage 1: layer-0 transform ∥ CSR fill (independent, co-scheduled)
    k_pre<<<2048, 256, 0, stream>>>(x, Ws0, Wn0, b0, yS0, yN0, src, dst, cnt, csr);

    // stage 2: layer-0 aggregate + layer-1 transform, fused (h never leaves regs)
    k_fagg0<<<FAGG_BLOCKS, 256, 0, stream>>>((const char*)yN0, yS0, cnt, csr,
                                             Ws1, Wn1, b1, yS1, yN1);

    // stage 3: final aggregate -> out
    k_aggf<<<aggBlocks, 256, 0, stream>>>((const char*)yN1, yS1, cnt, csr, out, 0);
}

// Round 4
// 189.541 us; speedup vs baseline: 1.1687x; 1.1687x over previous
//
#include <hip/hip_runtime.h>

#define N_NODES 50000
#define N_EDGES 800000
#define D 64
#define NSLICE 8
#define SLICE_N ((N_NODES + NSLICE - 1) / NSLICE)   // 6250
#define BCAP 64        // bucket capacity; deg ~ Poisson(16), P(deg>=64) ~ 1e-19
#define XF_BLOCKS 512  // k_xform: 2048 waves, ~6.1 groups/wave

// float -> bf16 (round-to-nearest-even), as raw ushort
__device__ __forceinline__ unsigned short f2bf(float f) {
    unsigned int u = __builtin_bit_cast(unsigned int, f);
    u += 0x7fffu + ((u >> 16) & 1u);
    return (unsigned short)(u >> 16);
}
__device__ __forceinline__ float bflo(unsigned int u) {
    return __builtin_bit_cast(float, u << 16);
}
__device__ __forceinline__ float bfhi(unsigned int u) {
    return __builtin_bit_cast(float, u & 0xffff0000u);
}

// ---------------- OLD transform body (k_pre's fused layer-0 role ONLY) ----------
// lane = output column, W column in 64 VGPRs, h rows as wave-uniform float4
// (scalarized to s_load -> serialized constant-cache misses ~45us standalone).
// Kept in k_pre UNCHANGED this round: swapping it would raise k_pre's VGPR to
// ~160 and cap the co-scheduled fill role's occupancy. Isolated swap = next.
__device__ __forceinline__ void xform_body(const float* __restrict__ h,
        const float* __restrict__ Ws, const float* __restrict__ Wn,
        const float* __restrict__ b,
        float* __restrict__ yS, unsigned short* __restrict__ yN,
        int gwave, int nwaves, int lane) {
    int mat = gwave & 1;
    const float* W = mat ? Wn : Ws;

    float w[D];
#pragma unroll
    for (int k = 0; k < D; ++k) w[k] = W[k * D + lane];
    float bj = mat ? 0.f : b[lane];

    const int ngroups = (N_NODES + 3) / 4;   // 12500, exact
    for (int g = gwave >> 1; g < ngroups; g += (nwaves >> 1)) {
        const float* x0 = h + (size_t)(g * 4) * D;
        float a0 = bj, a1 = bj, a2 = bj, a3 = bj;
#pragma unroll
        for (int kq = 0; kq < 16; ++kq) {
            float4 v0 = *(const float4*)(x0 + 0 * D + kq * 4);
            float4 v1 = *(const float4*)(x0 + 1 * D + kq * 4);
            float4 v2 = *(const float4*)(x0 + 2 * D + kq * 4);
            float4 v3 = *(const float4*)(x0 + 3 * D + kq * 4);
            a0 = fmaf(v0.x, w[kq * 4 + 0], a0);
            a1 = fmaf(v1.x, w[kq * 4 + 0], a1);
            a2 = fmaf(v2.x, w[kq * 4 + 0], a2);
            a3 = fmaf(v3.x, w[kq * 4 + 0], a3);
            a0 = fmaf(v0.y, w[kq * 4 + 1], a0);
            a1 = fmaf(v1.y, w[kq * 4 + 1], a1);
            a2 = fmaf(v2.y, w[kq * 4 + 1], a2);
            a3 = fmaf(v3.y, w[kq * 4 + 1], a3);
            a0 = fmaf(v0.z, w[kq * 4 + 2], a0);
            a1 = fmaf(v1.z, w[kq * 4 + 2], a1);
            a2 = fmaf(v2.z, w[kq * 4 + 2], a2);
            a3 = fmaf(v3.z, w[kq * 4 + 2], a3);
            a0 = fmaf(v0.w, w[kq * 4 + 3], a0);
            a1 = fmaf(v1.w, w[kq * 4 + 3], a1);
            a2 = fmaf(v2.w, w[kq * 4 + 3], a2);
            a3 = fmaf(v3.w, w[kq * 4 + 3], a3);
        }
        size_t base = (size_t)(g * 4) * D + lane;
        if (mat) {
            yN[base + 0 * D] = f2bf(a0);
            yN[base + 1 * D] = f2bf(a1);
            yN[base + 2 * D] = f2bf(a2);
            yN[base + 3 * D] = f2bf(a3);
        } else {
            yS[base + 0 * D] = a0;
            yS[base + 1 * D] = a1;
            yS[base + 2 * D] = a2;
            yS[base + 3 * D] = a3;
        }
    }
}

// ---------------- FUSED stage 1: layer-0 transform (blocks 0..1023) ∥ CSR fill ----
// FROZEN at R11 (slice s pinned to XCD s via bid&7; int4 edge loads). 46.8us.
__global__ __launch_bounds__(256) void k_pre(const float* __restrict__ x,
        const float* __restrict__ Ws0, const float* __restrict__ Wn0,
        const float* __restrict__ b0,
        float* __restrict__ yS, unsigned short* __restrict__ yN,
        const int* __restrict__ src, const int* __restrict__ dst,
        int* __restrict__ cnt, int* __restrict__ csr) {
    int bid = (int)blockIdx.x;
    if (bid < 1024) {
        int lane = threadIdx.x & 63;
        int gwave = __builtin_amdgcn_readfirstlane(bid * 4 + (int)(threadIdx.x >> 6));
        xform_body(x, Ws0, Wn0, b0, yS, yN, gwave, 4096, lane);
    } else {
        int slice = bid & 7;                 // 1024 % 8 == 0 -> slice == XCD id
        int lo = slice * SLICE_N, hi = lo + SLICE_N;
        int gblk = (bid - 1024) >> 3;        // 0..127 within the slice
        const int4* d4p = (const int4*)dst;
        const int4* s4p = (const int4*)src;
        const int NV = N_EDGES / 4;          // 200000, exact
        for (int v = gblk * 256 + (int)threadIdx.x; v < NV; v += 128 * 256) {
            int4 d4 = d4p[v];
            int4 s4 = s4p[v];
            if (d4.x >= lo && d4.x < hi) { int p = atomicAdd(&cnt[d4.x], 1); csr[(d4.x << 6) + p] = s4.x; }
            if (d4.y >= lo && d4.y < hi) { int p = atomicAdd(&cnt[d4.y], 1); csr[(d4.y << 6) + p] = s4.y; }
            if (d4.z >= lo && d4.z < hi) { int p = atomicAdd(&cnt[d4.z], 1); csr[(d4.z << 6) + p] = s4.z; }
            if (d4.w >= lo && d4.w < hi) { int p = atomicAdd(&cnt[d4.w], 1); csr[(d4.w << 6) + p] = s4.w; }
        }
    }
}

// ---------------- layer-1 transform, R14: readlane-broadcast, no uniform loads ----
// R12/R13 lesson: ANY wave-uniform streamed operand scalarizes to s_load and
// serializes at ~300cyc/miss (~45us). Here BOTH W matrices live in VGPRs
// (128 regs, loaded once per wave with lane-varying loads) and h is read with
// ONE lane-varying uint4 load per 4-row group (1KB/wave-instr, coalesced,
// parallel misses; next group prefetched). h[row][k] reaches all lanes via
// v_readlane from lane (row<<4)|(k>>2), component k&3 — VALU only.
// Per group: 1 load + 256 readlane + 512 fma; chip VALU floor ~8us.
// Ascending-k, one fma per k per accumulator -> bit-identical outputs.
__global__ __launch_bounds__(256) void k_xform(const float* __restrict__ h,
        const float* __restrict__ Ws, const float* __restrict__ Wn,
        const float* __restrict__ b,
        float* __restrict__ yS, unsigned short* __restrict__ yN) {
    int lane = threadIdx.x & 63;
    int gwave = __builtin_amdgcn_readfirstlane((int)((blockIdx.x * blockDim.x + threadIdx.x) >> 6));
    const int NW = (XF_BLOCKS * 256) >> 6;   // 2048 waves

    float ws[D], wn[D];
#pragma unroll
    for (int k = 0; k < D; ++k) ws[k] = Ws[k * D + lane];
#pragma unroll
    for (int k = 0; k < D; ++k) wn[k] = Wn[k * D + lane];
    float bj = b[lane];

    const int NG = N_NODES / 4;              // 12500, exact
    int g = gwave;
    if (g >= NG) return;
    uint4 xv = *(const uint4*)(h + (size_t)g * (4 * D) + lane * 4);
    for (; g < NG; g += NW) {
        int gn = g + NW; if (gn >= NG) gn = g;            // uniform clamp
        uint4 xn = *(const uint4*)(h + (size_t)gn * (4 * D) + lane * 4);
#pragma unroll
        for (int r = 0; r < 4; ++r) {
            float as = bj, an = 0.f;
#pragma unroll
            for (int k = 0; k < D; ++k) {
                unsigned comp = ((k & 3) == 0) ? xv.x : ((k & 3) == 1) ? xv.y
                              : ((k & 3) == 2) ? xv.z : xv.w;
                unsigned hb = (unsigned)__builtin_amdgcn_readlane((int)comp, (r << 4) | (k >> 2));
                float hk = __builtin_bit_cast(float, hb);
                as = fmaf(hk, ws[k], as);
                an = fmaf(hk, wn[k], an);
            }
            size_t row = (size_t)(g * 4 + r);
            yS[row * D + lane] = as;
            yN[row * D + lane] = f2bf(an);
        }
        xv = xn;
    }
}

// ---------------- fused mean-aggregate + self + epilogue (FROZEN since R10) ----------
__global__ __launch_bounds__(256) void k_aggf(const char* __restrict__ yN,
        const float* __restrict__ yS,
        const int* __restrict__ cnt, const int* __restrict__ csr,
        float* __restrict__ out, int relu) {
    int node = __builtin_amdgcn_readfirstlane((blockIdx.x * blockDim.x + threadIdx.x) >> 6);
    int lane = threadIdx.x & 63;
    int q = lane >> 3;          // edge sub-slot 0..7
    int fq = lane & 7;          // uint4 slot within the 128 B row
    int deg = cnt[node];
    const int* bucket = csr + (node << 6);
    unsigned foff = (unsigned)fq * 16u;

    float s0 = 0.f, s1 = 0.f, s2 = 0.f, s3 = 0.f;
    float s4 = 0.f, s5 = 0.f, s6 = 0.f, s7 = 0.f;

#define ROUND16(E0)                                                         \
    {                                                                       \
        int i0 = (E0) + q, i1 = i0 + 8;                                     \
        int b0 = bucket[i0], b1 = bucket[i1];                               \
        unsigned a0 = (i0 < deg) ? ((unsigned)b0 << 7) : 0u;                \
        unsigned a1 = (i1 < deg) ? ((unsigned)b1 << 7) : 0u;                \
        float m0 = (i0 < deg) ? 1.f : 0.f;                                  \
        float m1 = (i1 < deg) ? 1.f : 0.f;                                  \
        uint4 u0 = *(const uint4*)(yN + a0 + foff);                         \
        uint4 u1 = *(const uint4*)(yN + a1 + foff);                         \
        s0 = fmaf(m0, bflo(u0.x), s0); s0 = fmaf(m1, bflo(u1.x), s0);       \
        s1 = fmaf(m0, bfhi(u0.x), s1); s1 = fmaf(m1, bfhi(u1.x), s1);       \
        s2 = fmaf(m0, bflo(u0.y), s2); s2 = fmaf(m1, bflo(u1.y), s2);       \
        s3 = fmaf(m0, bfhi(u0.y), s3); s3 = fmaf(m1, bfhi(u1.y), s3);       \
        s4 = fmaf(m0, bflo(u0.z), s4); s4 = fmaf(m1, bflo(u1.z), s4);       \
        s5 = fmaf(m0, bfhi(u0.z), s5); s5 = fmaf(m1, bfhi(u1.z), s5);       \
        s6 = fmaf(m0, bflo(u0.w), s6); s6 = fmaf(m1, bflo(u1.w), s6);       \
        s7 = fmaf(m0, bfhi(u0.w), s7); s7 = fmaf(m1, bfhi(u1.w), s7);       \
    }

    ROUND16(0)                          // deg<=16: 53% of nodes stop here
    if (deg > 16) ROUND16(16)           // ~44%
    if (deg > 32) {                     // ~3%
        ROUND16(32)
        if (deg > 48) ROUND16(48)       // ~1e-4
    }
#undef ROUND16

    s0 += __shfl_xor(s0, 8, 64); s0 += __shfl_xor(s0, 16, 64); s0 += __shfl_xor(s0, 32, 64);
    s1 += __shfl_xor(s1, 8, 64); s1 += __shfl_xor(s1, 16, 64); s1 += __shfl_xor(s1, 32, 64);
    s2 += __shfl_xor(s2, 8, 64); s2 += __shfl_xor(s2, 16, 64); s2 += __shfl_xor(s2, 32, 64);
    s3 += __shfl_xor(s3, 8, 64); s3 += __shfl_xor(s3, 16, 64); s3 += __shfl_xor(s3, 32, 64);
    s4 += __shfl_xor(s4, 8, 64); s4 += __shfl_xor(s4, 16, 64); s4 += __shfl_xor(s4, 32, 64);
    s5 += __shfl_xor(s5, 8, 64); s5 += __shfl_xor(s5, 16, 64); s5 += __shfl_xor(s5, 32, 64);
    s6 += __shfl_xor(s6, 8, 64); s6 += __shfl_xor(s6, 16, 64); s6 += __shfl_xor(s6, 32, 64);
    s7 += __shfl_xor(s7, 8, 64); s7 += __shfl_xor(s7, 16, 64); s7 += __shfl_xor(s7, 32, 64);

    float sv = (q == 0) ? s0 : (q == 1) ? s1 : (q == 2) ? s2 : (q == 3) ? s3
             : (q == 4) ? s4 : (q == 5) ? s5 : (q == 6) ? s6 : s7;
    int f = fq * 8 + q;                      // feature this lane writes
    float self = yS[(size_t)node * D + f];
    float inv = 1.0f / fmaxf((float)deg, 1.0f);
    float acc = self + sv * inv;
    if (relu) acc = fmaxf(acc, 0.f);
    out[(size_t)node * D + f] = acc;
}

extern "C" void kernel_launch(void* const* d_in, const int* in_sizes, int n_in,
                              void* d_out, int out_size, void* d_ws, size_t ws_size,
                              hipStream_t stream) {
    const float* x   = (const float*)d_in[0];
    const int*   src = (const int*)d_in[1];
    const int*   dst = (const int*)d_in[2];
    const float* Ws0 = (const float*)d_in[3];
    const float* Wn0 = (const float*)d_in[4];
    const float* b0  = (const float*)d_in[5];
    const float* Ws1 = (const float*)d_in[6];
    const float* Wn1 = (const float*)d_in[7];
    const float* b1  = (const float*)d_in[8];
    float* out = (float*)d_out;

    // workspace layout (R11 layout restored: single yS/yN reused across layers)
    char* p = (char*)d_ws;
    float*          yS  = (float*)p;          p += (size_t)N_NODES * D * sizeof(float);
    unsigned short* yN  = (unsigned short*)p; p += (size_t)N_NODES * D * sizeof(unsigned short);
    int* cnt = (int*)p;                       p += (size_t)N_NODES * sizeof(int);
    int* csr = (int*)p;                       p += (size_t)N_NODES * BCAP * sizeof(int);

    const int aggBlocks = (N_NODES + 3) / 4;     // 12500: wave per node, exact

    // tiny cnt zero (200 KB), stream-ordered before the fused stage
    hipMemsetAsync(cnt, 0, (size_t)N_NODES * sizeof(int), stream);

    // stage 1: layer-0 transform ∥ CSR fill (independent, co-scheduled)
    k_pre<<<2048, 256, 0, stream>>>(x, Ws0, Wn0, b0, yS, yN, src, dst, cnt, csr);

    // layer 0 aggregate -> h in d_out
    k_aggf<<<aggBlocks, 256, 0, stream>>>((const char*)yN, yS, cnt, csr, out, 1);

    // layer 1 transform (readlane body) + aggregate -> d_out
    k_xform<<<XF_BLOCKS, 256, 0, stream>>>(out, Ws1, Wn1, b1, yS, yN);
    k_aggf<<<aggBlocks, 256, 0, stream>>>((const char*)yN, yS, cnt, csr, out, 0);
}

// Round 5
// 184.702 us; speedup vs baseline: 1.1993x; 1.0262x over previous
//
#include <hip/hip_runtime.h>

#define N_NODES 50000
#define N_EDGES 800000
#define D 64
#define NSLICE 8
#define SLICE_N ((N_NODES + NSLICE - 1) / NSLICE)   // 6250
#define BCAP 64        // bucket capacity; deg ~ Poisson(16), P(deg>=64) ~ 1e-19
#define XF_BLOCKS 512  // k_xform: 2048 waves, ~6.1 groups/wave

// float -> bf16 (round-to-nearest-even), as raw ushort
__device__ __forceinline__ unsigned short f2bf(float f) {
    unsigned int u = __builtin_bit_cast(unsigned int, f);
    u += 0x7fffu + ((u >> 16) & 1u);
    return (unsigned short)(u >> 16);
}
__device__ __forceinline__ float bflo(unsigned int u) {
    return __builtin_bit_cast(float, u << 16);
}
__device__ __forceinline__ float bfhi(unsigned int u) {
    return __builtin_bit_cast(float, u & 0xffff0000u);
}

// ---------------- transform body (k_pre's fused layer-0 role ONLY, FROZEN) ----------
__device__ __forceinline__ void xform_body(const float* __restrict__ h,
        const float* __restrict__ Ws, const float* __restrict__ Wn,
        const float* __restrict__ b,
        float* __restrict__ yS, unsigned short* __restrict__ yN,
        int gwave, int nwaves, int lane) {
    int mat = gwave & 1;
    const float* W = mat ? Wn : Ws;

    float w[D];
#pragma unroll
    for (int k = 0; k < D; ++k) w[k] = W[k * D + lane];
    float bj = mat ? 0.f : b[lane];

    const int ngroups = (N_NODES + 3) / 4;   // 12500, exact
    for (int g = gwave >> 1; g < ngroups; g += (nwaves >> 1)) {
        const float* x0 = h + (size_t)(g * 4) * D;
        float a0 = bj, a1 = bj, a2 = bj, a3 = bj;
#pragma unroll
        for (int kq = 0; kq < 16; ++kq) {
            float4 v0 = *(const float4*)(x0 + 0 * D + kq * 4);
            float4 v1 = *(const float4*)(x0 + 1 * D + kq * 4);
            float4 v2 = *(const float4*)(x0 + 2 * D + kq * 4);
            float4 v3 = *(const float4*)(x0 + 3 * D + kq * 4);
            a0 = fmaf(v0.x, w[kq * 4 + 0], a0);
            a1 = fmaf(v1.x, w[kq * 4 + 0], a1);
            a2 = fmaf(v2.x, w[kq * 4 + 0], a2);
            a3 = fmaf(v3.x, w[kq * 4 + 0], a3);
            a0 = fmaf(v0.y, w[kq * 4 + 1], a0);
            a1 = fmaf(v1.y, w[kq * 4 + 1], a1);
            a2 = fmaf(v2.y, w[kq * 4 + 1], a2);
            a3 = fmaf(v3.y, w[kq * 4 + 1], a3);
            a0 = fmaf(v0.z, w[kq * 4 + 2], a0);
            a1 = fmaf(v1.z, w[kq * 4 + 2], a1);
            a2 = fmaf(v2.z, w[kq * 4 + 2], a2);
            a3 = fmaf(v3.z, w[kq * 4 + 2], a3);
            a0 = fmaf(v0.w, w[kq * 4 + 3], a0);
            a1 = fmaf(v1.w, w[kq * 4 + 3], a1);
            a2 = fmaf(v2.w, w[kq * 4 + 3], a2);
            a3 = fmaf(v3.w, w[kq * 4 + 3], a3);
        }
        size_t base = (size_t)(g * 4) * D + lane;
        if (mat) {
            yN[base + 0 * D] = f2bf(a0);
            yN[base + 1 * D] = f2bf(a1);
            yN[base + 2 * D] = f2bf(a2);
            yN[base + 3 * D] = f2bf(a3);
        } else {
            yS[base + 0 * D] = a0;
            yS[base + 1 * D] = a1;
            yS[base + 2 * D] = a2;
            yS[base + 3 * D] = a3;
        }
    }
}

// ---------------- FUSED stage 1: layer-0 transform ∥ CSR fill (FROZEN, R11) ----------
__global__ __launch_bounds__(256) void k_pre(const float* __restrict__ x,
        const float* __restrict__ Ws0, const float* __restrict__ Wn0,
        const float* __restrict__ b0,
        float* __restrict__ yS, unsigned short* __restrict__ yN,
        const int* __restrict__ src, const int* __restrict__ dst,
        int* __restrict__ cnt, int* __restrict__ csr) {
    int bid = (int)blockIdx.x;
    if (bid < 1024) {
        int lane = threadIdx.x & 63;
        int gwave = __builtin_amdgcn_readfirstlane(bid * 4 + (int)(threadIdx.x >> 6));
        xform_body(x, Ws0, Wn0, b0, yS, yN, gwave, 4096, lane);
    } else {
        int slice = bid & 7;                 // 1024 % 8 == 0 -> slice == XCD id
        int lo = slice * SLICE_N, hi = lo + SLICE_N;
        int gblk = (bid - 1024) >> 3;        // 0..127 within the slice
        const int4* d4p = (const int4*)dst;
        const int4* s4p = (const int4*)src;
        const int NV = N_EDGES / 4;          // 200000, exact
        for (int v = gblk * 256 + (int)threadIdx.x; v < NV; v += 128 * 256) {
            int4 d4 = d4p[v];
            int4 s4 = s4p[v];
            if (d4.x >= lo && d4.x < hi) { int p = atomicAdd(&cnt[d4.x], 1); csr[(d4.x << 6) + p] = s4.x; }
            if (d4.y >= lo && d4.y < hi) { int p = atomicAdd(&cnt[d4.y], 1); csr[(d4.y << 6) + p] = s4.y; }
            if (d4.z >= lo && d4.z < hi) { int p = atomicAdd(&cnt[d4.z], 1); csr[(d4.z << 6) + p] = s4.z; }
            if (d4.w >= lo && d4.w < hi) { int p = atomicAdd(&cnt[d4.w], 1); csr[(d4.w << 6) + p] = s4.w; }
        }
    }
}

// ---------------- layer-1 transform (R14 readlane body, FROZEN, ~9us) ----------
__global__ __launch_bounds__(256) void k_xform(const float* __restrict__ h,
        const float* __restrict__ Ws, const float* __restrict__ Wn,
        const float* __restrict__ b,
        float* __restrict__ yS, unsigned short* __restrict__ yN) {
    int lane = threadIdx.x & 63;
    int gwave = __builtin_amdgcn_readfirstlane((int)((blockIdx.x * blockDim.x + threadIdx.x) >> 6));
    const int NW = (XF_BLOCKS * 256) >> 6;   // 2048 waves

    float ws[D], wn[D];
#pragma unroll
    for (int k = 0; k < D; ++k) ws[k] = Ws[k * D + lane];
#pragma unroll
    for (int k = 0; k < D; ++k) wn[k] = Wn[k * D + lane];
    float bj = b[lane];

    const int NG = N_NODES / 4;              // 12500, exact
    int g = gwave;
    if (g >= NG) return;
    uint4 xv = *(const uint4*)(h + (size_t)g * (4 * D) + lane * 4);
    for (; g < NG; g += NW) {
        int gn = g + NW; if (gn >= NG) gn = g;            // uniform clamp
        uint4 xn = *(const uint4*)(h + (size_t)gn * (4 * D) + lane * 4);
#pragma unroll
        for (int r = 0; r < 4; ++r) {
            float as = bj, an = 0.f;
#pragma unroll
            for (int k = 0; k < D; ++k) {
                unsigned comp = ((k & 3) == 0) ? xv.x : ((k & 3) == 1) ? xv.y
                              : ((k & 3) == 2) ? xv.z : xv.w;
                unsigned hb = (unsigned)__builtin_amdgcn_readlane((int)comp, (r << 4) | (k >> 2));
                float hk = __builtin_bit_cast(float, hb);
                as = fmaf(hk, ws[k], as);
                an = fmaf(hk, wn[k], an);
            }
            size_t row = (size_t)(g * 4 + r);
            yS[row * D + lane] = as;
            yN[row * D + lane] = f2bf(an);
        }
        xv = xn;
    }
}

// ---------------- fused mean-aggregate + self + epilogue ----------
// R15 change (ONLY change this round): first 32 edges are UNCONDITIONAL.
// Old form branched after 16 (`if (deg>16)`), so round 2's bucket-load ->
// gather chain waited on a wave-uniform branch: ~2 serialized L3 round-trips
// per node (~2000 cyc). Straight-line ROUND16(0);ROUND16(16) lets the
// compiler cluster 4 bucket loads + 8 gathers before any consuming FMA
// (8 outstanding gathers vs 2). deg<=16 nodes (53%) issue masked gathers of
// row 0 — one broadcast-cached line, ~free. Masked slots add fmaf(0,finite,s)
// = s exactly and live-edge order is unchanged -> bit-identical output.
__global__ __launch_bounds__(256) void k_aggf(const char* __restrict__ yN,
        const float* __restrict__ yS,
        const int* __restrict__ cnt, const int* __restrict__ csr,
        float* __restrict__ out, int relu) {
    int node = __builtin_amdgcn_readfirstlane((blockIdx.x * blockDim.x + threadIdx.x) >> 6);
    int lane = threadIdx.x & 63;
    int q = lane >> 3;          // edge sub-slot 0..7
    int fq = lane & 7;          // uint4 slot within the 128 B row
    int deg = cnt[node];
    const int* bucket = csr + (node << 6);
    unsigned foff = (unsigned)fq * 16u;

    float s0 = 0.f, s1 = 0.f, s2 = 0.f, s3 = 0.f;
    float s4 = 0.f, s5 = 0.f, s6 = 0.f, s7 = 0.f;

#define ROUND16(E0)                                                         \
    {                                                                       \
        int i0 = (E0) + q, i1 = i0 + 8;                                     \
        int b0 = bucket[i0], b1 = bucket[i1];                               \
        unsigned a0 = (i0 < deg) ? ((unsigned)b0 << 7) : 0u;                \
        unsigned a1 = (i1 < deg) ? ((unsigned)b1 << 7) : 0u;                \
        float m0 = (i0 < deg) ? 1.f : 0.f;                                  \
        float m1 = (i1 < deg) ? 1.f : 0.f;                                  \
        uint4 u0 = *(const uint4*)(yN + a0 + foff);                         \
        uint4 u1 = *(const uint4*)(yN + a1 + foff);                         \
        s0 = fmaf(m0, bflo(u0.x), s0); s0 = fmaf(m1, bflo(u1.x), s0);       \
        s1 = fmaf(m0, bfhi(u0.x), s1); s1 = fmaf(m1, bfhi(u1.x), s1);       \
        s2 = fmaf(m0, bflo(u0.y), s2); s2 = fmaf(m1, bflo(u1.y), s2);       \
        s3 = fmaf(m0, bfhi(u0.y), s3); s3 = fmaf(m1, bfhi(u1.y), s3);       \
        s4 = fmaf(m0, bflo(u0.z), s4); s4 = fmaf(m1, bflo(u1.z), s4);       \
        s5 = fmaf(m0, bfhi(u0.z), s5); s5 = fmaf(m1, bfhi(u1.z), s5);       \
        s6 = fmaf(m0, bflo(u0.w), s6); s6 = fmaf(m1, bflo(u1.w), s6);       \
        s7 = fmaf(m0, bfhi(u0.w), s7); s7 = fmaf(m1, bfhi(u1.w), s7);       \
    }

    ROUND16(0)                          // unconditional: covers deg<=32 (97%)
    ROUND16(16)                         // unconditional: 8 gathers in flight
    if (deg > 32) {                     // ~3%
        ROUND16(32)
        if (deg > 48) ROUND16(48)       // ~1e-4
    }
#undef ROUND16

    s0 += __shfl_xor(s0, 8, 64); s0 += __shfl_xor(s0, 16, 64); s0 += __shfl_xor(s0, 32, 64);
    s1 += __shfl_xor(s1, 8, 64); s1 += __shfl_xor(s1, 16, 64); s1 += __shfl_xor(s1, 32, 64);
    s2 += __shfl_xor(s2, 8, 64); s2 += __shfl_xor(s2, 16, 64); s2 += __shfl_xor(s2, 32, 64);
    s3 += __shfl_xor(s3, 8, 64); s3 += __shfl_xor(s3, 16, 64); s3 += __shfl_xor(s3, 32, 64);
    s4 += __shfl_xor(s4, 8, 64); s4 += __shfl_xor(s4, 16, 64); s4 += __shfl_xor(s4, 32, 64);
    s5 += __shfl_xor(s5, 8, 64); s5 += __shfl_xor(s5, 16, 64); s5 += __shfl_xor(s5, 32, 64);
    s6 += __shfl_xor(s6, 8, 64); s6 += __shfl_xor(s6, 16, 64); s6 += __shfl_xor(s6, 32, 64);
    s7 += __shfl_xor(s7, 8, 64); s7 += __shfl_xor(s7, 16, 64); s7 += __shfl_xor(s7, 32, 64);

    float sv = (q == 0) ? s0 : (q == 1) ? s1 : (q == 2) ? s2 : (q == 3) ? s3
             : (q == 4) ? s4 : (q == 5) ? s5 : (q == 6) ? s6 : s7;
    int f = fq * 8 + q;                      // feature this lane writes
    float self = yS[(size_t)node * D + f];
    float inv = 1.0f / fmaxf((float)deg, 1.0f);
    float acc = self + sv * inv;
    if (relu) acc = fmaxf(acc, 0.f);
    out[(size_t)node * D + f] = acc;
}

extern "C" void kernel_launch(void* const* d_in, const int* in_sizes, int n_in,
                              void* d_out, int out_size, void* d_ws, size_t ws_size,
                              hipStream_t stream) {
    const float* x   = (const float*)d_in[0];
    const int*   src = (const int*)d_in[1];
    const int*   dst = (const int*)d_in[2];
    const float* Ws0 = (const float*)d_in[3];
    const float* Wn0 = (const float*)d_in[4];
    const float* b0  = (const float*)d_in[5];
    const float* Ws1 = (const float*)d_in[6];
    const float* Wn1 = (const float*)d_in[7];
    const float* b1  = (const float*)d_in[8];
    float* out = (float*)d_out;

    // workspace layout
    char* p = (char*)d_ws;
    float*          yS  = (float*)p;          p += (size_t)N_NODES * D * sizeof(float);
    unsigned short* yN  = (unsigned short*)p; p += (size_t)N_NODES * D * sizeof(unsigned short);
    int* cnt = (int*)p;                       p += (size_t)N_NODES * sizeof(int);
    int* csr = (int*)p;                       p += (size_t)N_NODES * BCAP * sizeof(int);

    const int aggBlocks = (N_NODES + 3) / 4;     // 12500: wave per node, exact

    // tiny cnt zero (200 KB), stream-ordered before the fused stage
    hipMemsetAsync(cnt, 0, (size_t)N_NODES * sizeof(int), stream);

    // stage 1: layer-0 transform ∥ CSR fill (independent, co-scheduled)
    k_pre<<<2048, 256, 0, stream>>>(x, Ws0, Wn0, b0, yS, yN, src, dst, cnt, csr);

    // layer 0 aggregate -> h in d_out
    k_aggf<<<aggBlocks, 256, 0, stream>>>((const char*)yN, yS, cnt, csr, out, 1);

    // layer 1 transform + aggregate -> d_out
    k_xform<<<XF_BLOCKS, 256, 0, stream>>>(out, Ws1, Wn1, b1, yS, yN);
    k_aggf<<<aggBlocks, 256, 0, stream>>>((const char*)yN, yS, cnt, csr, out, 0);
}

// Round 6
// 183.558 us; speedup vs baseline: 1.2068x; 1.0062x over previous
//
#include <hip/hip_runtime.h>

#define N_NODES 50000
#define N_EDGES 800000
#define D 64
#define NSLICE 4
#define SLICE_N ((N_NODES + NSLICE - 1) / NSLICE)   // 12500
#define BCAP 64        // bucket capacity; deg ~ Poisson(16), P(deg>=64) ~ 1e-19
#define XF_BLOCKS 512  // k_xform: 2048 waves, ~6.1 groups/wave
#define PRE_XF_BLOCKS 768      // transform role: 3072 waves
#define PRE_FILL_BLOCKS 1280   // fill role: 320 blocks/slice

// float -> bf16 (round-to-nearest-even), as raw ushort
__device__ __forceinline__ unsigned short f2bf(float f) {
    unsigned int u = __builtin_bit_cast(unsigned int, f);
    u += 0x7fffu + ((u >> 16) & 1u);
    return (unsigned short)(u >> 16);
}
__device__ __forceinline__ float bflo(unsigned int u) {
    return __builtin_bit_cast(float, u << 16);
}
__device__ __forceinline__ float bfhi(unsigned int u) {
    return __builtin_bit_cast(float, u & 0xffff0000u);
}

// ---------------- transform body (k_pre's fused layer-0 role ONLY, FROZEN) ----------
__device__ __forceinline__ void xform_body(const float* __restrict__ h,
        const float* __restrict__ Ws, const float* __restrict__ Wn,
        const float* __restrict__ b,
        float* __restrict__ yS, unsigned short* __restrict__ yN,
        int gwave, int nwaves, int lane) {
    int mat = gwave & 1;
    const float* W = mat ? Wn : Ws;

    float w[D];
#pragma unroll
    for (int k = 0; k < D; ++k) w[k] = W[k * D + lane];
    float bj = mat ? 0.f : b[lane];

    const int ngroups = (N_NODES + 3) / 4;   // 12500, exact
    for (int g = gwave >> 1; g < ngroups; g += (nwaves >> 1)) {
        const float* x0 = h + (size_t)(g * 4) * D;
        float a0 = bj, a1 = bj, a2 = bj, a3 = bj;
#pragma unroll
        for (int kq = 0; kq < 16; ++kq) {
            float4 v0 = *(const float4*)(x0 + 0 * D + kq * 4);
            float4 v1 = *(const float4*)(x0 + 1 * D + kq * 4);
            float4 v2 = *(const float4*)(x0 + 2 * D + kq * 4);
            float4 v3 = *(const float4*)(x0 + 3 * D + kq * 4);
            a0 = fmaf(v0.x, w[kq * 4 + 0], a0);
            a1 = fmaf(v1.x, w[kq * 4 + 0], a1);
            a2 = fmaf(v2.x, w[kq * 4 + 0], a2);
            a3 = fmaf(v3.x, w[kq * 4 + 0], a3);
            a0 = fmaf(v0.y, w[kq * 4 + 1], a0);
            a1 = fmaf(v1.y, w[kq * 4 + 1], a1);
            a2 = fmaf(v2.y, w[kq * 4 + 1], a2);
            a3 = fmaf(v3.y, w[kq * 4 + 1], a3);
            a0 = fmaf(v0.z, w[kq * 4 + 2], a0);
            a1 = fmaf(v1.z, w[kq * 4 + 2], a1);
            a2 = fmaf(v2.z, w[kq * 4 + 2], a2);
            a3 = fmaf(v3.z, w[kq * 4 + 2], a3);
            a0 = fmaf(v0.w, w[kq * 4 + 3], a0);
            a1 = fmaf(v1.w, w[kq * 4 + 3], a1);
            a2 = fmaf(v2.w, w[kq * 4 + 3], a2);
            a3 = fmaf(v3.w, w[kq * 4 + 3], a3);
        }
        size_t base = (size_t)(g * 4) * D + lane;
        if (mat) {
            yN[base + 0 * D] = f2bf(a0);
            yN[base + 1 * D] = f2bf(a1);
            yN[base + 2 * D] = f2bf(a2);
            yN[base + 3 * D] = f2bf(a3);
        } else {
            yS[base + 0 * D] = a0;
            yS[base + 1 * D] = a1;
            yS[base + 2 * D] = a2;
            yS[base + 3 * D] = a3;
        }
    }
}

// ---------------- FUSED stage 1: layer-0 transform ∥ CSR fill ----------
// R16 changes (ONLY changes this round):
//  (1) NSLICE 8 -> 4. cnt atomics are device-scope -> fabric-level REGARDLESS
//      of slicing, so slicing's real wins are fill parallelism + csr
//      write-merging in local L2. The slice cost is the redundant edge scan:
//      NSLICE x 12.8 MB (8x = 102 MB of L3-served src/dst reads). 4 slices
//      halve that to 51 MB; per-slice csr range 12500*256B = 3.2 MB still
//      fits a 4 MB L2, so write-merging survives. Each slice runs on XCD
//      pair {s, s+4} (fid&3 with fid%8 spread).
//  (2) rebalance 768 transform / 1280 fill blocks (transform is ~14-19us of
//      full-chip work; fill is the long pole -> 62% of residency).
__global__ __launch_bounds__(256) void k_pre(const float* __restrict__ x,
        const float* __restrict__ Ws0, const float* __restrict__ Wn0,
        const float* __restrict__ b0,
        float* __restrict__ yS, unsigned short* __restrict__ yN,
        const int* __restrict__ src, const int* __restrict__ dst,
        int* __restrict__ cnt, int* __restrict__ csr) {
    int bid = (int)blockIdx.x;
    if (bid < PRE_XF_BLOCKS) {
        int lane = threadIdx.x & 63;
        int gwave = __builtin_amdgcn_readfirstlane(bid * 4 + (int)(threadIdx.x >> 6));
        xform_body(x, Ws0, Wn0, b0, yS, yN, gwave, PRE_XF_BLOCKS * 4, lane);
    } else {
        int fid = bid - PRE_XF_BLOCKS;        // 0..1279
        int slice = fid & 3;                  // slice s on XCD pair {s, s+4}
        int lo = slice * SLICE_N, hi = lo + SLICE_N;
        int gblk = fid >> 2;                  // 0..319 within the slice
        const int4* d4p = (const int4*)dst;
        const int4* s4p = (const int4*)src;
        const int NV = N_EDGES / 4;           // 200000, exact
        const int STRIDE = (PRE_FILL_BLOCKS / 4) * 256;   // 81920
        for (int v = gblk * 256 + (int)threadIdx.x; v < NV; v += STRIDE) {
            int4 d4 = d4p[v];
            int4 s4 = s4p[v];
            if (d4.x >= lo && d4.x < hi) { int p = atomicAdd(&cnt[d4.x], 1); csr[(d4.x << 6) + p] = s4.x; }
            if (d4.y >= lo && d4.y < hi) { int p = atomicAdd(&cnt[d4.y], 1); csr[(d4.y << 6) + p] = s4.y; }
            if (d4.z >= lo && d4.z < hi) { int p = atomicAdd(&cnt[d4.z], 1); csr[(d4.z << 6) + p] = s4.z; }
            if (d4.w >= lo && d4.w < hi) { int p = atomicAdd(&cnt[d4.w], 1); csr[(d4.w << 6) + p] = s4.w; }
        }
    }
}

// ---------------- layer-1 transform (R14 readlane body, FROZEN) ----------
__global__ __launch_bounds__(256) void k_xform(const float* __restrict__ h,
        const float* __restrict__ Ws, const float* __restrict__ Wn,
        const float* __restrict__ b,
        float* __restrict__ yS, unsigned short* __restrict__ yN) {
    int lane = threadIdx.x & 63;
    int gwave = __builtin_amdgcn_readfirstlane((int)((blockIdx.x * blockDim.x + threadIdx.x) >> 6));
    const int NW = (XF_BLOCKS * 256) >> 6;   // 2048 waves

    float ws[D], wn[D];
#pragma unroll
    for (int k = 0; k < D; ++k) ws[k] = Ws[k * D + lane];
#pragma unroll
    for (int k = 0; k < D; ++k) wn[k] = Wn[k * D + lane];
    float bj = b[lane];

    const int NG = N_NODES / 4;              // 12500, exact
    int g = gwave;
    if (g >= NG) return;
    uint4 xv = *(const uint4*)(h + (size_t)g * (4 * D) + lane * 4);
    for (; g < NG; g += NW) {
        int gn = g + NW; if (gn >= NG) gn = g;            // uniform clamp
        uint4 xn = *(const uint4*)(h + (size_t)gn * (4 * D) + lane * 4);
#pragma unroll
        for (int r = 0; r < 4; ++r) {
            float as = bj, an = 0.f;
#pragma unroll
            for (int k = 0; k < D; ++k) {
                unsigned comp = ((k & 3) == 0) ? xv.x : ((k & 3) == 1) ? xv.y
                              : ((k & 3) == 2) ? xv.z : xv.w;
                unsigned hb = (unsigned)__builtin_amdgcn_readlane((int)comp, (r << 4) | (k >> 2));
                float hk = __builtin_bit_cast(float, hb);
                as = fmaf(hk, ws[k], as);
                an = fmaf(hk, wn[k], an);
            }
            size_t row = (size_t)(g * 4 + r);
            yS[row * D + lane] = as;
            yN[row * D + lane] = f2bf(an);
        }
        xv = xn;
    }
}

// ---------------- fused mean-aggregate + self + epilogue (R15 body, FROZEN) ----------
__global__ __launch_bounds__(256) void k_aggf(const char* __restrict__ yN,
        const float* __restrict__ yS,
        const int* __restrict__ cnt, const int* __restrict__ csr,
        float* __restrict__ out, int relu) {
    int node = __builtin_amdgcn_readfirstlane((blockIdx.x * blockDim.x + threadIdx.x) >> 6);
    int lane = threadIdx.x & 63;
    int q = lane >> 3;          // edge sub-slot 0..7
    int fq = lane & 7;          // uint4 slot within the 128 B row
    int deg = cnt[node];
    const int* bucket = csr + (node << 6);
    unsigned foff = (unsigned)fq * 16u;

    float s0 = 0.f, s1 = 0.f, s2 = 0.f, s3 = 0.f;
    float s4 = 0.f, s5 = 0.f, s6 = 0.f, s7 = 0.f;

#define ROUND16(E0)                                                         \
    {                                                                       \
        int i0 = (E0) + q, i1 = i0 + 8;                                     \
        int b0 = bucket[i0], b1 = bucket[i1];                               \
        unsigned a0 = (i0 < deg) ? ((unsigned)b0 << 7) : 0u;                \
        unsigned a1 = (i1 < deg) ? ((unsigned)b1 << 7) : 0u;                \
        float m0 = (i0 < deg) ? 1.f : 0.f;                                  \
        float m1 = (i1 < deg) ? 1.f : 0.f;                                  \
        uint4 u0 = *(const uint4*)(yN + a0 + foff);                         \
        uint4 u1 = *(const uint4*)(yN + a1 + foff);                         \
        s0 = fmaf(m0, bflo(u0.x), s0); s0 = fmaf(m1, bflo(u1.x), s0);       \
        s1 = fmaf(m0, bfhi(u0.x), s1); s1 = fmaf(m1, bfhi(u1.x), s1);       \
        s2 = fmaf(m0, bflo(u0.y), s2); s2 = fmaf(m1, bflo(u1.y), s2);       \
        s3 = fmaf(m0, bfhi(u0.y), s3); s3 = fmaf(m1, bfhi(u1.y), s3);       \
        s4 = fmaf(m0, bflo(u0.z), s4); s4 = fmaf(m1, bflo(u1.z), s4);       \
        s5 = fmaf(m0, bfhi(u0.z), s5); s5 = fmaf(m1, bfhi(u1.z), s5);       \
        s6 = fmaf(m0, bflo(u0.w), s6); s6 = fmaf(m1, bflo(u1.w), s6);       \
        s7 = fmaf(m0, bfhi(u0.w), s7); s7 = fmaf(m1, bfhi(u1.w), s7);       \
    }

    ROUND16(0)                          // unconditional: covers deg<=32 (97%)
    ROUND16(16)                         // unconditional: 8 gathers in flight
    if (deg > 32) {                     // ~3%
        ROUND16(32)
        if (deg > 48) ROUND16(48)       // ~1e-4
    }
#undef ROUND16

    s0 += __shfl_xor(s0, 8, 64); s0 += __shfl_xor(s0, 16, 64); s0 += __shfl_xor(s0, 32, 64);
    s1 += __shfl_xor(s1, 8, 64); s1 += __shfl_xor(s1, 16, 64); s1 += __shfl_xor(s1, 32, 64);
    s2 += __shfl_xor(s2, 8, 64); s2 += __shfl_xor(s2, 16, 64); s2 += __shfl_xor(s2, 32, 64);
    s3 += __shfl_xor(s3, 8, 64); s3 += __shfl_xor(s3, 16, 64); s3 += __shfl_xor(s3, 32, 64);
    s4 += __shfl_xor(s4, 8, 64); s4 += __shfl_xor(s4, 16, 64); s4 += __shfl_xor(s4, 32, 64);
    s5 += __shfl_xor(s5, 8, 64); s5 += __shfl_xor(s5, 16, 64); s5 += __shfl_xor(s5, 32, 64);
    s6 += __shfl_xor(s6, 8, 64); s6 += __shfl_xor(s6, 16, 64); s6 += __shfl_xor(s6, 32, 64);
    s7 += __shfl_xor(s7, 8, 64); s7 += __shfl_xor(s7, 16, 64); s7 += __shfl_xor(s7, 32, 64);

    float sv = (q == 0) ? s0 : (q == 1) ? s1 : (q == 2) ? s2 : (q == 3) ? s3
             : (q == 4) ? s4 : (q == 5) ? s5 : (q == 6) ? s6 : s7;
    int f = fq * 8 + q;                      // feature this lane writes
    float self = yS[(size_t)node * D + f];
    float inv = 1.0f / fmaxf((float)deg, 1.0f);
    float acc = self + sv * inv;
    if (relu) acc = fmaxf(acc, 0.f);
    out[(size_t)node * D + f] = acc;
}

extern "C" void kernel_launch(void* const* d_in, const int* in_sizes, int n_in,
                              void* d_out, int out_size, void* d_ws, size_t ws_size,
                              hipStream_t stream) {
    const float* x   = (const float*)d_in[0];
    const int*   src = (const int*)d_in[1];
    const int*   dst = (const int*)d_in[2];
    const float* Ws0 = (const float*)d_in[3];
    const float* Wn0 = (const float*)d_in[4];
    const float* b0  = (const float*)d_in[5];
    const float* Ws1 = (const float*)d_in[6];
    const float* Wn1 = (const float*)d_in[7];
    const float* b1  = (const float*)d_in[8];
    float* out = (float*)d_out;

    // workspace layout
    char* p = (char*)d_ws;
    float*          yS  = (float*)p;          p += (size_t)N_NODES * D * sizeof(float);
    unsigned short* yN  = (unsigned short*)p; p += (size_t)N_NODES * D * sizeof(unsigned short);
    int* cnt = (int*)p;                       p += (size_t)N_NODES * sizeof(int);
    int* csr = (int*)p;                       p += (size_t)N_NODES * BCAP * sizeof(int);

    const int aggBlocks = (N_NODES + 3) / 4;     // 12500: wave per node, exact

    // tiny cnt zero (200 KB), stream-ordered before the fused stage
    hipMemsetAsync(cnt, 0, (size_t)N_NODES * sizeof(int), stream);

    // stage 1: layer-0 transform ∥ CSR fill (independent, co-scheduled)
    k_pre<<<PRE_XF_BLOCKS + PRE_FILL_BLOCKS, 256, 0, stream>>>(
        x, Ws0, Wn0, b0, yS, yN, src, dst, cnt, csr);

    // layer 0 aggregate -> h in d_out
    k_aggf<<<aggBlocks, 256, 0, stream>>>((const char*)yN, yS, cnt, csr, out, 1);

    // layer 1 transform + aggregate -> d_out
    k_xform<<<XF_BLOCKS, 256, 0, stream>>>(out, Ws1, Wn1, b1, yS, yN);
    k_aggf<<<aggBlocks, 256, 0, stream>>>((const char*)yN, yS, cnt, csr, out, 0);
}

// Round 7
// 182.964 us; speedup vs baseline: 1.2107x; 1.0032x over previous
//
#include <hip/hip_runtime.h>

#define N_NODES 50000
#define N_EDGES 800000
#define D 64
#define NSLICE 4
#define SLICE_N ((N_NODES + NSLICE - 1) / NSLICE)   // 12500
#define BCAP 64        // bucket capacity; deg ~ Poisson(16), P(deg>=64) ~ 1e-19
#define XF_BLOCKS 1536 // k_xform: 6144 waves = 6/SIMD (VGPR ~80), 3072/mat, ~16 rows/wave
#define PRE_XF_BLOCKS 768      // transform role: 3072 waves
#define PRE_FILL_BLOCKS 1280   // fill role: 320 blocks/slice

// float -> bf16 (round-to-nearest-even), as raw ushort
__device__ __forceinline__ unsigned short f2bf(float f) {
    unsigned int u = __builtin_bit_cast(unsigned int, f);
    u += 0x7fffu + ((u >> 16) & 1u);
    return (unsigned short)(u >> 16);
}
__device__ __forceinline__ float bflo(unsigned int u) {
    return __builtin_bit_cast(float, u << 16);
}
__device__ __forceinline__ float bfhi(unsigned int u) {
    return __builtin_bit_cast(float, u & 0xffff0000u);
}

// ---------------- transform body (k_pre's fused layer-0 role ONLY, FROZEN) ----------
__device__ __forceinline__ void xform_body(const float* __restrict__ h,
        const float* __restrict__ Ws, const float* __restrict__ Wn,
        const float* __restrict__ b,
        float* __restrict__ yS, unsigned short* __restrict__ yN,
        int gwave, int nwaves, int lane) {
    int mat = gwave & 1;
    const float* W = mat ? Wn : Ws;

    float w[D];
#pragma unroll
    for (int k = 0; k < D; ++k) w[k] = W[k * D + lane];
    float bj = mat ? 0.f : b[lane];

    const int ngroups = (N_NODES + 3) / 4;   // 12500, exact
    for (int g = gwave >> 1; g < ngroups; g += (nwaves >> 1)) {
        const float* x0 = h + (size_t)(g * 4) * D;
        float a0 = bj, a1 = bj, a2 = bj, a3 = bj;
#pragma unroll
        for (int kq = 0; kq < 16; ++kq) {
            float4 v0 = *(const float4*)(x0 + 0 * D + kq * 4);
            float4 v1 = *(const float4*)(x0 + 1 * D + kq * 4);
            float4 v2 = *(const float4*)(x0 + 2 * D + kq * 4);
            float4 v3 = *(const float4*)(x0 + 3 * D + kq * 4);
            a0 = fmaf(v0.x, w[kq * 4 + 0], a0);
            a1 = fmaf(v1.x, w[kq * 4 + 0], a1);
            a2 = fmaf(v2.x, w[kq * 4 + 0], a2);
            a3 = fmaf(v3.x, w[kq * 4 + 0], a3);
            a0 = fmaf(v0.y, w[kq * 4 + 1], a0);
            a1 = fmaf(v1.y, w[kq * 4 + 1], a1);
            a2 = fmaf(v2.y, w[kq * 4 + 1], a2);
            a3 = fmaf(v3.y, w[kq * 4 + 1], a3);
            a0 = fmaf(v0.z, w[kq * 4 + 2], a0);
            a1 = fmaf(v1.z, w[kq * 4 + 2], a1);
            a2 = fmaf(v2.z, w[kq * 4 + 2], a2);
            a3 = fmaf(v3.z, w[kq * 4 + 2], a3);
            a0 = fmaf(v0.w, w[kq * 4 + 3], a0);
            a1 = fmaf(v1.w, w[kq * 4 + 3], a1);
            a2 = fmaf(v2.w, w[kq * 4 + 3], a2);
            a3 = fmaf(v3.w, w[kq * 4 + 3], a3);
        }
        size_t base = (size_t)(g * 4) * D + lane;
        if (mat) {
            yN[base + 0 * D] = f2bf(a0);
            yN[base + 1 * D] = f2bf(a1);
            yN[base + 2 * D] = f2bf(a2);
            yN[base + 3 * D] = f2bf(a3);
        } else {
            yS[base + 0 * D] = a0;
            yS[base + 1 * D] = a1;
            yS[base + 2 * D] = a2;
            yS[base + 3 * D] = a3;
        }
    }
}

// ---------------- FUSED stage 1: layer-0 transform ∥ CSR fill (FROZEN, R16) ----------
__global__ __launch_bounds__(256) void k_pre(const float* __restrict__ x,
        const float* __restrict__ Ws0, const float* __restrict__ Wn0,
        const float* __restrict__ b0,
        float* __restrict__ yS, unsigned short* __restrict__ yN,
        const int* __restrict__ src, const int* __restrict__ dst,
        int* __restrict__ cnt, int* __restrict__ csr) {
    int bid = (int)blockIdx.x;
    if (bid < PRE_XF_BLOCKS) {
        int lane = threadIdx.x & 63;
        int gwave = __builtin_amdgcn_readfirstlane(bid * 4 + (int)(threadIdx.x >> 6));
        xform_body(x, Ws0, Wn0, b0, yS, yN, gwave, PRE_XF_BLOCKS * 4, lane);
    } else {
        int fid = bid - PRE_XF_BLOCKS;        // 0..1279
        int slice = fid & 3;                  // slice s on XCD pair {s, s+4}
        int lo = slice * SLICE_N, hi = lo + SLICE_N;
        int gblk = fid >> 2;                  // 0..319 within the slice
        const int4* d4p = (const int4*)dst;
        const int4* s4p = (const int4*)src;
        const int NV = N_EDGES / 4;           // 200000, exact
        const int STRIDE = (PRE_FILL_BLOCKS / 4) * 256;   // 81920
        for (int v = gblk * 256 + (int)threadIdx.x; v < NV; v += STRIDE) {
            int4 d4 = d4p[v];
            int4 s4 = s4p[v];
            if (d4.x >= lo && d4.x < hi) { int p = atomicAdd(&cnt[d4.x], 1); csr[(d4.x << 6) + p] = s4.x; }
            if (d4.y >= lo && d4.y < hi) { int p = atomicAdd(&cnt[d4.y], 1); csr[(d4.y << 6) + p] = s4.y; }
            if (d4.z >= lo && d4.z < hi) { int p = atomicAdd(&cnt[d4.z], 1); csr[(d4.z << 6) + p] = s4.z; }
            if (d4.w >= lo && d4.w < hi) { int p = atomicAdd(&cnt[d4.w], 1); csr[(d4.w << 6) + p] = s4.w; }
        }
    }
}

// ---------------- layer-1 transform, R17: SGPR-operand FMA at real occupancy ----------
// Budget recalc exposed this kernel at ~28us, not ~9: old geometry ran 2
// waves/SIMD (XF_BLOCKS=512) with a 64-deep serial fma chain (256 cyc/row)
// and readlane overhead doubling VALU ops; the pre-R14 variant additionally
// carried __launch_bounds__(256,4), forcing VGPR<=128 and spilling w[64].
// New structure targets the 5.2us chip FMA floor:
//  - W column per lane in 64 VGPRs (loaded once per wave, mat = wid&1);
//  - h row read wave-uniform -> compiler merges to s_load_dwordx16 (4 SMEM
//    per 64 FMAs, vs R12's 64 per 64) feeding v_fmac v,s,v directly;
//  - 1536 blocks = 6144 waves = 6/SIMD (~80 VGPR, no launch_bounds cap):
//    six independent 256-cyc acc chains interleave per SIMD -> VALU-bound.
// Ascending k, bj-seeded, one fma per k -> BIT-IDENTICAL to prior bodies.
__global__ __launch_bounds__(256) void k_xform(const float* __restrict__ h,
        const float* __restrict__ Ws, const float* __restrict__ Wn,
        const float* __restrict__ b,
        float* __restrict__ yS, unsigned short* __restrict__ yN) {
    int lane = threadIdx.x & 63;
    int wid = __builtin_amdgcn_readfirstlane((int)((blockIdx.x * blockDim.x + threadIdx.x) >> 6));
    int mat = wid & 1;
    const float* W = mat ? Wn : Ws;

    float w[D];
#pragma unroll
    for (int k = 0; k < D; ++k) w[k] = W[k * D + lane];
    float bj = mat ? 0.f : b[lane];

    const int NWM = (XF_BLOCKS * 256 / 64) >> 1;   // 3072 waves per mat
    for (int row = wid >> 1; row < N_NODES; row += NWM) {
        const float* hr = h + (size_t)row * D;     // wave-uniform base
        float acc = bj;
#pragma unroll
        for (int k = 0; k < D; ++k) acc = fmaf(hr[k], w[k], acc);
        if (mat) yN[(size_t)row * D + lane] = f2bf(acc);
        else     yS[(size_t)row * D + lane] = acc;
    }
}

// ---------------- fused mean-aggregate + self + epilogue (R15 body, FROZEN) ----------
__global__ __launch_bounds__(256) void k_aggf(const char* __restrict__ yN,
        const float* __restrict__ yS,
        const int* __restrict__ cnt, const int* __restrict__ csr,
        float* __restrict__ out, int relu) {
    int node = __builtin_amdgcn_readfirstlane((blockIdx.x * blockDim.x + threadIdx.x) >> 6);
    int lane = threadIdx.x & 63;
    int q = lane >> 3;          // edge sub-slot 0..7
    int fq = lane & 7;          // uint4 slot within the 128 B row
    int deg = cnt[node];
    const int* bucket = csr + (node << 6);
    unsigned foff = (unsigned)fq * 16u;

    float s0 = 0.f, s1 = 0.f, s2 = 0.f, s3 = 0.f;
    float s4 = 0.f, s5 = 0.f, s6 = 0.f, s7 = 0.f;

#define ROUND16(E0)                                                         \
    {                                                                       \
        int i0 = (E0) + q, i1 = i0 + 8;                                     \
        int b0 = bucket[i0], b1 = bucket[i1];                               \
        unsigned a0 = (i0 < deg) ? ((unsigned)b0 << 7) : 0u;                \
        unsigned a1 = (i1 < deg) ? ((unsigned)b1 << 7) : 0u;                \
        float m0 = (i0 < deg) ? 1.f : 0.f;                                  \
        float m1 = (i1 < deg) ? 1.f : 0.f;                                  \
        uint4 u0 = *(const uint4*)(yN + a0 + foff);                         \
        uint4 u1 = *(const uint4*)(yN + a1 + foff);                         \
        s0 = fmaf(m0, bflo(u0.x), s0); s0 = fmaf(m1, bflo(u1.x), s0);       \
        s1 = fmaf(m0, bfhi(u0.x), s1); s1 = fmaf(m1, bfhi(u1.x), s1);       \
        s2 = fmaf(m0, bflo(u0.y), s2); s2 = fmaf(m1, bflo(u1.y), s2);       \
        s3 = fmaf(m0, bfhi(u0.y), s3); s3 = fmaf(m1, bfhi(u1.y), s3);       \
        s4 = fmaf(m0, bflo(u0.z), s4); s4 = fmaf(m1, bflo(u1.z), s4);       \
        s5 = fmaf(m0, bfhi(u0.z), s5); s5 = fmaf(m1, bfhi(u1.z), s5);       \
        s6 = fmaf(m0, bflo(u0.w), s6); s6 = fmaf(m1, bflo(u1.w), s6);       \
        s7 = fmaf(m0, bfhi(u0.w), s7); s7 = fmaf(m1, bfhi(u1.w), s7);       \
    }

    ROUND16(0)                          // unconditional: covers deg<=32 (97%)
    ROUND16(16)                         // unconditional: 8 gathers in flight
    if (deg > 32) {                     // ~3%
        ROUND16(32)
        if (deg > 48) ROUND16(48)       // ~1e-4
    }
#undef ROUND16

    s0 += __shfl_xor(s0, 8, 64); s0 += __shfl_xor(s0, 16, 64); s0 += __shfl_xor(s0, 32, 64);
    s1 += __shfl_xor(s1, 8, 64); s1 += __shfl_xor(s1, 16, 64); s1 += __shfl_xor(s1, 32, 64);
    s2 += __shfl_xor(s2, 8, 64); s2 += __shfl_xor(s2, 16, 64); s2 += __shfl_xor(s2, 32, 64);
    s3 += __shfl_xor(s3, 8, 64); s3 += __shfl_xor(s3, 16, 64); s3 += __shfl_xor(s3, 32, 64);
    s4 += __shfl_xor(s4, 8, 64); s4 += __shfl_xor(s4, 16, 64); s4 += __shfl_xor(s4, 32, 64);
    s5 += __shfl_xor(s5, 8, 64); s5 += __shfl_xor(s5, 16, 64); s5 += __shfl_xor(s5, 32, 64);
    s6 += __shfl_xor(s6, 8, 64); s6 += __shfl_xor(s6, 16, 64); s6 += __shfl_xor(s6, 32, 64);
    s7 += __shfl_xor(s7, 8, 64); s7 += __shfl_xor(s7, 16, 64); s7 += __shfl_xor(s7, 32, 64);

    float sv = (q == 0) ? s0 : (q == 1) ? s1 : (q == 2) ? s2 : (q == 3) ? s3
             : (q == 4) ? s4 : (q == 5) ? s5 : (q == 6) ? s6 : s7;
    int f = fq * 8 + q;                      // feature this lane writes
    float self = yS[(size_t)node * D + f];
    float inv = 1.0f / fmaxf((float)deg, 1.0f);
    float acc = self + sv * inv;
    if (relu) acc = fmaxf(acc, 0.f);
    out[(size_t)node * D + f] = acc;
}

extern "C" void kernel_launch(void* const* d_in, const int* in_sizes, int n_in,
                              void* d_out, int out_size, void* d_ws, size_t ws_size,
                              hipStream_t stream) {
    const float* x   = (const float*)d_in[0];
    const int*   src = (const int*)d_in[1];
    const int*   dst = (const int*)d_in[2];
    const float* Ws0 = (const float*)d_in[3];
    const float* Wn0 = (const float*)d_in[4];
    const float* b0  = (const float*)d_in[5];
    const float* Ws1 = (const float*)d_in[6];
    const float* Wn1 = (const float*)d_in[7];
    const float* b1  = (const float*)d_in[8];
    float* out = (float*)d_out;

    // workspace layout
    char* p = (char*)d_ws;
    float*          yS  = (float*)p;          p += (size_t)N_NODES * D * sizeof(float);
    unsigned short* yN  = (unsigned short*)p; p += (size_t)N_NODES * D * sizeof(unsigned short);
    int* cnt = (int*)p;                       p += (size_t)N_NODES * sizeof(int);
    int* csr = (int*)p;                       p += (size_t)N_NODES * BCAP * sizeof(int);

    const int aggBlocks = (N_NODES + 3) / 4;     // 12500: wave per node, exact

    // tiny cnt zero (200 KB), stream-ordered before the fused stage
    hipMemsetAsync(cnt, 0, (size_t)N_NODES * sizeof(int), stream);

    // stage 1: layer-0 transform ∥ CSR fill (independent, co-scheduled)
    k_pre<<<PRE_XF_BLOCKS + PRE_FILL_BLOCKS, 256, 0, stream>>>(
        x, Ws0, Wn0, b0, yS, yN, src, dst, cnt, csr);

    // layer 0 aggregate -> h in d_out
    k_aggf<<<aggBlocks, 256, 0, stream>>>((const char*)yN, yS, cnt, csr, out, 1);

    // layer 1 transform + aggregate -> d_out
    k_xform<<<XF_BLOCKS, 256, 0, stream>>>(out, Ws1, Wn1, b1, yS, yN);
    k_aggf<<<aggBlocks, 256, 0, stream>>>((const char*)yN, yS, cnt, csr, out, 0);
}